// Round 1
// baseline (2771.940 us; speedup 1.0000x reference)
//
#include <hip/hip_runtime.h>
#include <math.h>

#define NSEQ   128
#define DIMH   64
#define NHEAD  8
#define NBH    32          // B*H
#define LDIM   64
#define DMODEL 512
#define SCALE  0.125f      // 64^-0.5
#define TAUINV 1000.0f     // 1/tau
#define TEMPV  10.0f

// ws layout (float offsets)
#define OFF_X    0          // [32][128][64]
#define OFF_Y    262144
#define OFF_V    524288
#define OFF_COST 786432     // [32][128][128]
#define OFF_SWDS 1310720    // [32][64]
#define OFF_W    1312768    // [32][64]
#define OFF_OH   1314816    // [4*128][512]
// total 1576960 floats = 6.31 MB

// ---------------- K1: qkv = x @ w_qkv^T, split/scale into X, Y, V ----------------
__global__ __launch_bounds__(256) void k_qkv(const float* __restrict__ x,
                                             const float* __restrict__ wqkv,
                                             float* __restrict__ ws) {
  __shared__ float xs[64][65];
  __shared__ float wsm[64][65];
  const int r0 = blockIdx.x * 64;
  const int c0 = blockIdx.y * 64;
  const int t = threadIdx.x;
  const int tr = (t >> 4) << 2;
  const int tc = (t & 15) << 2;
  float acc[4][4] = {};
  for (int k0 = 0; k0 < 512; k0 += 64) {
    for (int idx = t; idx < 64 * 64; idx += 256) {
      int i = idx >> 6, j = idx & 63;
      xs[i][j]  = x[(size_t)(r0 + i) * 512 + k0 + j];
      wsm[i][j] = wqkv[(size_t)(c0 + i) * 512 + k0 + j];
    }
    __syncthreads();
    for (int kk = 0; kk < 64; ++kk) {
      float a[4], b[4];
#pragma unroll
      for (int u = 0; u < 4; ++u) { a[u] = xs[tr + u][kk]; b[u] = wsm[tc + u][kk]; }
#pragma unroll
      for (int u = 0; u < 4; ++u)
#pragma unroll
        for (int w = 0; w < 4; ++w) acc[u][w] += a[u] * b[w];
    }
    __syncthreads();
  }
  float* X = ws + OFF_X; float* Y = ws + OFF_Y; float* V = ws + OFF_V;
#pragma unroll
  for (int u = 0; u < 4; ++u) {
    int r = r0 + tr + u; int b = r >> 7, n = r & 127;
#pragma unroll
    for (int w = 0; w < 4; ++w) {
      int c = c0 + tc + w;
      float val = acc[u][w];
      int which = c >> 9;         // 0:q 1:k 2:v
      int cc = c & 511;
      int h = cc >> 6, d = cc & 63;
      size_t dst = (((size_t)b * NHEAD + h) * NSEQ + n) * DIMH + d;
      if (which == 0)      X[dst] = val * SCALE;
      else if (which == 1) Y[dst] = val * SCALE;
      else                 V[dst] = val;
    }
  }
}

// ---------------- K2: cost[bh][i][j] = ||X_i - Y_j||_2 ----------------
__global__ __launch_bounds__(256) void k_cost(float* __restrict__ ws) {
  extern __shared__ float sm[];
  float* Xs = sm;            // 128*65 (padded)
  float* Ys = sm + 128 * 65; // 128*64
  float* xx = Ys + 128 * 64; // 128
  float* yy = xx + 128;      // 128
  const int bh = blockIdx.x;
  const int t = threadIdx.x;
  const float* Xg = ws + OFF_X + (size_t)bh * NSEQ * DIMH;
  const float* Yg = ws + OFF_Y + (size_t)bh * NSEQ * DIMH;
  for (int idx = t; idx < NSEQ * DIMH; idx += 256) {
    int i = idx >> 6, j = idx & 63;
    Xs[i * 65 + j] = Xg[idx];
    Ys[idx] = Yg[idx];
  }
  __syncthreads();
  if (t < 128) {
    float s = 0;
    for (int d = 0; d < 64; ++d) { float v = Xs[t * 65 + d]; s += v * v; }
    xx[t] = s;
  } else {
    int j = t - 128; float s = 0;
    for (int d = 0; d < 64; ++d) { float v = Ys[j * 64 + d]; s += v * v; }
    yy[j] = s;
  }
  __syncthreads();
  const int i = t >> 1, j0 = (t & 1) << 6;
  float xr[64];
#pragma unroll
  for (int d = 0; d < 64; ++d) xr[d] = Xs[i * 65 + d];
  float* C = ws + OFF_COST + (size_t)bh * NSEQ * NSEQ + (size_t)i * NSEQ + j0;
  for (int jj = 0; jj < 64; ++jj) {
    float dot = 0;
#pragma unroll
    for (int d = 0; d < 64; ++d) dot += xr[d] * Ys[(j0 + jj) * 64 + d];
    float sq = xx[i] + yy[j0 + jj] - 2.f * dot;
    C[jj] = sqrtf(fmaxf(sq, 0.f));
  }
}

// ------------- build soft permutation matrix P (128x128) in LDS -------------
__device__ __forceinline__ void build_P(const float* __restrict__ colbase, int stride,
                                        float* __restrict__ P, float* __restrict__ s,
                                        float* __restrict__ ss, int t) {
  if (t < NSEQ) s[t] = colbase[(size_t)t * stride];
  __syncthreads();
  if (t < NSEQ) {
    float v = s[t];
    int rank = 0;
    for (int m = 0; m < NSEQ; ++m) {
      float u = s[m];
      rank += (u > v) || (u == v && m < t);
    }
    ss[rank] = v;   // descending sorted values
  }
  __syncthreads();
  const int wid = t >> 6, lane = t & 63;
  for (int k = wid; k < NSEQ; k += 4) {
    float sk = ss[k];
    float d1 = s[lane] - sk, d2 = s[lane + 64] - sk;
    float z1 = -TAUINV * d1 * d1, z2 = -TAUINV * d2 * d2;
    float m = fmaxf(z1, z2);
#pragma unroll
    for (int off = 32; off >= 1; off >>= 1) m = fmaxf(m, __shfl_xor(m, off));
    float e1 = __expf(z1 - m), e2 = __expf(z2 - m);
    float sum = e1 + e2;
#pragma unroll
    for (int off = 32; off >= 1; off >>= 1) sum += __shfl_xor(sum, off);
    float inv = 1.f / sum;
    P[k * NSEQ + lane] = e1 * inv;
    P[k * NSEQ + lane + 64] = e2 * inv;
  }
  __syncthreads();
}

// ---------------- K3: swds[bh][l] = <Pu_l^T Pv_l, C> ----------------
__global__ __launch_bounds__(256) void k_phase1(float* __restrict__ ws) {
  extern __shared__ float sm[];
  float* Pu = sm; float* Pv = sm + 16384;
  float* s = sm + 32768; float* ss = sm + 32896;
  const int bhl = blockIdx.x;
  const int bh = bhl >> 6, l = bhl & 63;
  const int t = threadIdx.x;
  build_P(ws + OFF_X + (size_t)bh * NSEQ * DIMH + l, DIMH, Pu, s, ss, t);
  build_P(ws + OFF_Y + (size_t)bh * NSEQ * DIMH + l, DIMH, Pv, s, ss, t);
  const int i0 = (t >> 3) << 2;   // 0..124 step 4
  const int j0 = (t & 7) << 4;    // 0..112 step 16
  float acc[4][16] = {};
  for (int k = 0; k < NSEQ; ++k) {
    float pu[4], pv[16];
#pragma unroll
    for (int u = 0; u < 4; ++u) pu[u] = Pu[k * NSEQ + i0 + u];
#pragma unroll
    for (int w = 0; w < 16; ++w) pv[w] = Pv[k * NSEQ + j0 + w];
#pragma unroll
    for (int u = 0; u < 4; ++u)
#pragma unroll
      for (int w = 0; w < 16; ++w) acc[u][w] += pu[u] * pv[w];
  }
  const float* C = ws + OFF_COST + (size_t)bh * NSEQ * NSEQ;
  float part = 0;
#pragma unroll
  for (int u = 0; u < 4; ++u)
#pragma unroll
    for (int w = 0; w < 16; ++w) part += acc[u][w] * C[(i0 + u) * NSEQ + j0 + w];
#pragma unroll
  for (int off = 32; off >= 1; off >>= 1) part += __shfl_xor(part, off);
  const int wid = t >> 6, lane = t & 63;
  if (lane == 0) s[wid] = part;
  __syncthreads();
  if (t == 0) ws[OFF_SWDS + bhl] = s[0] + s[1] + s[2] + s[3];
}

// ---------------- K4: weights = softmax(-TEMP*(swds-min)) over l ----------------
__global__ void k_weights(float* __restrict__ ws) {
  const int bh = blockIdx.x;
  const int l = threadIdx.x;   // 64 threads = 1 wave
  float v = ws[OFF_SWDS + bh * 64 + l];
  float mn = v;
#pragma unroll
  for (int off = 32; off >= 1; off >>= 1) mn = fminf(mn, __shfl_xor(mn, off));
  float e = __expf(-TEMPV * (v - mn));
  float sum = e;
#pragma unroll
  for (int off = 32; off >= 1; off >>= 1) sum += __shfl_xor(sum, off);
  ws[OFF_W + bh * 64 + l] = e / sum;
}

// ---------------- K5: attn += w_l * Pu_l^T Pv_l (atomic) ----------------
__global__ __launch_bounds__(256) void k_phase2(float* __restrict__ ws, float* __restrict__ attn) {
  extern __shared__ float sm[];
  float* Pu = sm; float* Pv = sm + 16384;
  float* s = sm + 32768; float* ss = sm + 32896;
  const int bhl = blockIdx.x;
  const int bh = bhl >> 6, l = bhl & 63;
  const int t = threadIdx.x;
  build_P(ws + OFF_X + (size_t)bh * NSEQ * DIMH + l, DIMH, Pu, s, ss, t);
  build_P(ws + OFF_Y + (size_t)bh * NSEQ * DIMH + l, DIMH, Pv, s, ss, t);
  const float wl = ws[OFF_W + bhl];
  const int i0 = (t >> 3) << 2;
  const int j0 = (t & 7) << 4;
  float acc[4][16] = {};
  for (int k = 0; k < NSEQ; ++k) {
    float pu[4], pv[16];
#pragma unroll
    for (int u = 0; u < 4; ++u) pu[u] = Pu[k * NSEQ + i0 + u];
#pragma unroll
    for (int w = 0; w < 16; ++w) pv[w] = Pv[k * NSEQ + j0 + w];
#pragma unroll
    for (int u = 0; u < 4; ++u)
#pragma unroll
      for (int w = 0; w < 16; ++w) acc[u][w] += pu[u] * pv[w];
  }
  float* A = attn + (size_t)bh * NSEQ * NSEQ;
#pragma unroll
  for (int u = 0; u < 4; ++u)
#pragma unroll
    for (int w = 0; w < 16; ++w)
      atomicAdd(&A[(i0 + u) * NSEQ + j0 + w], wl * acc[u][w]);
}

// ---------------- K6a: oh = attn @ V (per head), scattered to [b*n][512] ----------------
__global__ __launch_bounds__(256) void k_av(const float* __restrict__ attn, float* __restrict__ ws) {
  extern __shared__ float sm[];
  float* As = sm;                 // 128*129 padded
  float* Vs = sm + 128 * 129;     // 128*64
  const int bh = blockIdx.x; const int t = threadIdx.x;
  const float* Ag = attn + (size_t)bh * 16384;
  const float* Vg = ws + OFF_V + (size_t)bh * 8192;
  for (int idx = t; idx < 16384; idx += 256) {
    int i = idx >> 7, j = idx & 127;
    As[i * 129 + j] = Ag[idx];
  }
  for (int idx = t; idx < 8192; idx += 256) Vs[idx] = Vg[idx];
  __syncthreads();
  const int i = t >> 1, d0 = (t & 1) << 5;
  float acc[32] = {};
  for (int j = 0; j < NSEQ; ++j) {
    float a = As[i * 129 + j];
#pragma unroll
    for (int dd = 0; dd < 32; ++dd) acc[dd] += a * Vs[j * DIMH + d0 + dd];
  }
  const int b = bh >> 3, h = bh & 7;
  float* o = ws + OFF_OH + ((size_t)(b * NSEQ + i)) * DMODEL + h * DIMH + d0;
#pragma unroll
  for (int dd = 0; dd < 32; ++dd) o[dd] = acc[dd];
}

// ---------------- K6b: out = oh @ w_out^T + b_out ----------------
__global__ __launch_bounds__(256) void k_out(const float* __restrict__ oh,
                                             const float* __restrict__ wout,
                                             const float* __restrict__ bout,
                                             float* __restrict__ out) {
  __shared__ float as_[64][65];
  __shared__ float bs_[64][65];
  const int r0 = blockIdx.x * 64, c0 = blockIdx.y * 64;
  const int t = threadIdx.x;
  const int tr = (t >> 4) << 2, tc = (t & 15) << 2;
  float acc[4][4] = {};
  for (int k0 = 0; k0 < 512; k0 += 64) {
    for (int idx = t; idx < 64 * 64; idx += 256) {
      int i = idx >> 6, j = idx & 63;
      as_[i][j] = oh[(size_t)(r0 + i) * 512 + k0 + j];
      bs_[i][j] = wout[(size_t)(c0 + i) * 512 + k0 + j];
    }
    __syncthreads();
    for (int kk = 0; kk < 64; ++kk) {
      float a[4], b[4];
#pragma unroll
      for (int u = 0; u < 4; ++u) { a[u] = as_[tr + u][kk]; b[u] = bs_[tc + u][kk]; }
#pragma unroll
      for (int u = 0; u < 4; ++u)
#pragma unroll
        for (int w = 0; w < 4; ++w) acc[u][w] += a[u] * b[w];
    }
    __syncthreads();
  }
#pragma unroll
  for (int u = 0; u < 4; ++u)
#pragma unroll
    for (int w = 0; w < 4; ++w)
      out[(size_t)(r0 + tr + u) * 512 + c0 + tc + w] = acc[u][w] + bout[c0 + tc + w];
}

extern "C" void kernel_launch(void* const* d_in, const int* in_sizes, int n_in,
                              void* d_out, int out_size, void* d_ws, size_t ws_size,
                              hipStream_t stream) {
  (void)in_sizes; (void)n_in; (void)out_size; (void)ws_size;
  const float* x    = (const float*)d_in[0];
  const float* wqkv = (const float*)d_in[1];
  const float* wout = (const float*)d_in[2];
  const float* bout = (const float*)d_in[3];
  float* out  = (float*)d_out;           // [4,128,512] = 262144 floats
  float* attn = out + 262144;            // [4,8,128,128] = 524288 floats
  float* ws   = (float*)d_ws;

  hipMemsetAsync(attn, 0, 524288 * sizeof(float), stream);
  k_qkv<<<dim3(8, 24), 256, 0, stream>>>(x, wqkv, ws);
  k_cost<<<32, 256, (128 * 65 + 128 * 64 + 256) * 4, stream>>>(ws);
  k_phase1<<<2048, 256, 33024 * 4, stream>>>(ws);
  k_weights<<<32, 64, 0, stream>>>(ws);
  k_phase2<<<2048, 256, 33024 * 4, stream>>>(ws, attn);
  k_av<<<32, 256, (128 * 129 + 128 * 64) * 4, stream>>>(attn, ws);
  k_out<<<dim3(8, 8), 256, 0, stream>>>(ws + OFF_OH, wout, bout, out);
}

// Round 3
// 425.703 us; speedup vs baseline: 6.5114x; 6.5114x over previous
//
#include <hip/hip_runtime.h>
#include <math.h>

typedef _Float16 f16x8 __attribute__((ext_vector_type(8)));
typedef float f32x4 __attribute__((ext_vector_type(4)));

#define NSEQ   128
#define DIMH   64
#define NHEAD  8
#define DMODEL 512
#define SCALE  0.125f      // 64^-0.5
#define SPAD   136         // f16 elems per PT row (272B stride: frag reads 2-way=free)

// ws layout (float offsets)
#define OFF_X    0          // [32][128][64]
#define OFF_Y    262144
#define OFF_V    524288
#define OFF_COST 786432     // [32][128][128]
#define OFF_SWDS 1310720    // [32][64]
#define OFF_W    1312768    // [32][64]
#define OFF_OH   1314816    // [4*128][512]

#define PH_SMEM  72224      // 2*128*136*2 + (128*3+256+8)*4 -> 2 blocks/CU

// ---------------- K1: qkv = x @ w_qkv^T, split/scale into X, Y, V ----------------
__global__ __launch_bounds__(256) void k_qkv(const float* __restrict__ x,
                                             const float* __restrict__ wqkv,
                                             float* __restrict__ ws) {
  __shared__ float xs[64][65];
  __shared__ float wsm[64][65];
  const int r0 = blockIdx.x * 64;
  const int c0 = blockIdx.y * 64;
  const int t = threadIdx.x;
  const int tr = (t >> 4) << 2;
  const int tc = (t & 15) << 2;
  float acc[4][4] = {};
  for (int k0 = 0; k0 < 512; k0 += 64) {
    for (int idx = t; idx < 64 * 64; idx += 256) {
      int i = idx >> 6, j = idx & 63;
      xs[i][j]  = x[(size_t)(r0 + i) * 512 + k0 + j];
      wsm[i][j] = wqkv[(size_t)(c0 + i) * 512 + k0 + j];
    }
    __syncthreads();
    for (int kk = 0; kk < 64; ++kk) {
      float a[4], b[4];
#pragma unroll
      for (int u = 0; u < 4; ++u) { a[u] = xs[tr + u][kk]; b[u] = wsm[tc + u][kk]; }
#pragma unroll
      for (int u = 0; u < 4; ++u)
#pragma unroll
        for (int w = 0; w < 4; ++w) acc[u][w] += a[u] * b[w];
    }
    __syncthreads();
  }
  float* X = ws + OFF_X; float* Y = ws + OFF_Y; float* V = ws + OFF_V;
#pragma unroll
  for (int u = 0; u < 4; ++u) {
    int r = r0 + tr + u; int b = r >> 7, n = r & 127;
#pragma unroll
    for (int w = 0; w < 4; ++w) {
      int c = c0 + tc + w;
      float val = acc[u][w];
      int which = c >> 9;         // 0:q 1:k 2:v
      int cc = c & 511;
      int h = cc >> 6, d = cc & 63;
      size_t dst = (((size_t)b * NHEAD + h) * NSEQ + n) * DIMH + d;
      if (which == 0)      X[dst] = val * SCALE;
      else if (which == 1) Y[dst] = val * SCALE;
      else                 V[dst] = val;
    }
  }
}

// ---------------- K2: cost[bh][i][j] = ||X_i - Y_j||_2 ----------------
__global__ __launch_bounds__(256) void k_cost(float* __restrict__ ws) {
  extern __shared__ float sm[];
  float* Xs = sm;            // 128*65 (padded)
  float* Ys = sm + 128 * 65; // 128*64
  float* xx = Ys + 128 * 64; // 128
  float* yy = xx + 128;      // 128
  const int bh = blockIdx.x;
  const int t = threadIdx.x;
  const float* Xg = ws + OFF_X + (size_t)bh * NSEQ * DIMH;
  const float* Yg = ws + OFF_Y + (size_t)bh * NSEQ * DIMH;
  for (int idx = t; idx < NSEQ * DIMH; idx += 256) {
    int i = idx >> 6, j = idx & 63;
    Xs[i * 65 + j] = Xg[idx];
    Ys[idx] = Yg[idx];
  }
  __syncthreads();
  if (t < 128) {
    float s = 0;
    for (int d = 0; d < 64; ++d) { float v = Xs[t * 65 + d]; s += v * v; }
    xx[t] = s;
  } else {
    int j = t - 128; float s = 0;
    for (int d = 0; d < 64; ++d) { float v = Ys[j * 64 + d]; s += v * v; }
    yy[j] = s;
  }
  __syncthreads();
  const int i = t >> 1, j0 = (t & 1) << 6;
  float xr[64];
#pragma unroll
  for (int d = 0; d < 64; ++d) xr[d] = Xs[i * 65 + d];
  float* C = ws + OFF_COST + (size_t)bh * NSEQ * NSEQ + (size_t)i * NSEQ + j0;
  for (int jj = 0; jj < 64; ++jj) {
    float dot = 0;
#pragma unroll
    for (int d = 0; d < 64; ++d) dot += xr[d] * Ys[(j0 + jj) * 64 + d];
    float sq = xx[i] + yy[j0 + jj] - 2.f * dot;
    C[jj] = sqrtf(fmaxf(sq, 0.f));
  }
}

// Build TRANSPOSED soft-perm matrix PT[i][k] = P[k][i] in fp16 LDS.
// P[k][i] = softmax_i(-(s_i - sorted_k)^2/tau). Max logit is exactly 0
// (sorted_k equals some s_i) -> no max pass needed.
__device__ void build_PT(const float* __restrict__ col, _Float16* __restrict__ PT,
                         float* s_, float* ss_, float* inv_, float* den2, int t) {
  if (t < NSEQ) s_[t] = col[(size_t)t * DIMH];
  __syncthreads();
  if (t < NSEQ) {
    float v = s_[t];
    int rank = 0;
    for (int m = 0; m < NSEQ; ++m) {
      float u = s_[m];
      rank += (u > v) || (u == v && m < t);
    }
    ss_[rank] = v;   // descending sorted values
  }
  __syncthreads();
  {  // denominators: den[k] = sum_i exp(-1000*(s_i-ss_k)^2), split over 2 halves
    const int k = t & 127, half = t >> 7;
    const float sk = ss_[k];
    const int i0 = half << 6;
    float sum = 0.f;
    for (int i = 0; i < 64; ++i) {
      float d = s_[i0 + i] - sk;
      sum += __expf(-1000.f * d * d);
    }
    den2[(half << 7) + k] = sum;
  }
  __syncthreads();
  if (t < NSEQ) inv_[t] = 1.f / (den2[t] + den2[128 + t]);
  __syncthreads();
  {  // entries: thread t -> row i = t>>1, k half (t&1)*64; 16B f16 stores
    const int i = t >> 1, k0 = (t & 1) << 6;
    const float si = s_[i];
    for (int kb = 0; kb < 64; kb += 8) {
      f16x8 pk;
#pragma unroll
      for (int j = 0; j < 8; ++j) {
        const int k = k0 + kb + j;
        float d = si - ss_[k];
        pk[j] = (_Float16)(__expf(-1000.f * d * d) * inv_[k]);
      }
      *reinterpret_cast<f16x8*>(&PT[i * SPAD + k0 + kb]) = pk;
    }
  }
  __syncthreads();
}

// MFMA operand fragment: lane holds 8 contiguous k at row (baserow + lane&15),
// k-group (lane>>4)*8. Works for both A (rows of PuT) and B (rows of PvT).
__device__ __forceinline__ f16x8 fragPT(const _Float16* PT, int baserow, int k0, int lane) {
  return *reinterpret_cast<const f16x8*>(
      &PT[(baserow + (lane & 15)) * SPAD + k0 + ((lane >> 4) << 3)]);
}

// ---------------- K3: swds[bh][l] = <Pu_l^T Pv_l, C>  (MFMA) ----------------
__global__ __launch_bounds__(256) void k_phase1(float* __restrict__ ws) {
  extern __shared__ char smem[];
  _Float16* PuT = (_Float16*)smem;
  _Float16* PvT = PuT + NSEQ * SPAD;
  float* s_   = (float*)(PvT + NSEQ * SPAD);
  float* ss_  = s_ + 128;
  float* inv_ = ss_ + 128;
  float* den2 = inv_ + 128;   // 256
  float* red  = den2 + 256;   // 8
  const int bhl = blockIdx.x, bh = bhl >> 6, l = bhl & 63;
  const int t = threadIdx.x, w = t >> 6, lane = t & 63;
  build_PT(ws + OFF_X + (size_t)bh * NSEQ * DIMH + l, PuT, s_, ss_, inv_, den2, t);
  build_PT(ws + OFF_Y + (size_t)bh * NSEQ * DIMH + l, PvT, s_, ss_, inv_, den2, t);
  f32x4 acc[2][8];
#pragma unroll
  for (int a = 0; a < 2; ++a)
#pragma unroll
    for (int b = 0; b < 8; ++b) acc[a][b] = 0;
  const int r0 = w << 5;   // wave owns Gamma rows [r0, r0+32)
#pragma unroll
  for (int kc = 0; kc < 4; ++kc) {
    const int k0 = kc << 5;
    f16x8 a0 = fragPT(PuT, r0, k0, lane);
    f16x8 a1 = fragPT(PuT, r0 + 16, k0, lane);
#pragma unroll
    for (int fj = 0; fj < 8; ++fj) {
      f16x8 b = fragPT(PvT, fj << 4, k0, lane);
      acc[0][fj] = __builtin_amdgcn_mfma_f32_16x16x32_f16(a0, b, acc[0][fj], 0, 0, 0);
      acc[1][fj] = __builtin_amdgcn_mfma_f32_16x16x32_f16(a1, b, acc[1][fj], 0, 0, 0);
    }
  }
  // part = sum acc .* C   (C/D layout: col=lane&15, row=(lane>>4)*4+reg)
  const float* C = ws + OFF_COST + (size_t)bh * NSEQ * NSEQ;
  const int cr = r0 + ((lane >> 4) << 2), cc = lane & 15;
  float part = 0.f;
#pragma unroll
  for (int fi = 0; fi < 2; ++fi)
#pragma unroll
    for (int fj = 0; fj < 8; ++fj)
#pragma unroll
      for (int r = 0; r < 4; ++r)
        part += acc[fi][fj][r] * C[(cr + (fi << 4) + r) * NSEQ + (fj << 4) + cc];
#pragma unroll
  for (int off = 32; off >= 1; off >>= 1) part += __shfl_xor(part, off);
  if (lane == 0) red[w] = part;
  __syncthreads();
  if (t == 0) ws[OFF_SWDS + bhl] = red[0] + red[1] + red[2] + red[3];
}

// ---------------- K4: weights = softmax(-TEMP*(swds-min)) over l ----------------
__global__ void k_weights(float* __restrict__ ws) {
  const int bh = blockIdx.x;
  const int l = threadIdx.x;   // 64 threads = 1 wave
  float v = ws[OFF_SWDS + bh * 64 + l];
  float mn = v;
#pragma unroll
  for (int off = 32; off >= 1; off >>= 1) mn = fminf(mn, __shfl_xor(mn, off));
  float e = __expf(-10.f * (v - mn));
  float sum = e;
#pragma unroll
  for (int off = 32; off >= 1; off >>= 1) sum += __shfl_xor(sum, off);
  ws[OFF_W + bh * 64 + l] = e / sum;
}

// ------- K5: attn += sum_l w_l * Pu_l^T Pv_l  (MFMA; w_l applied in f32 regs) -------
__global__ __launch_bounds__(256) void k_phase2(float* __restrict__ ws, float* __restrict__ attn) {
  extern __shared__ char smem[];
  _Float16* PuT = (_Float16*)smem;
  _Float16* PvT = PuT + NSEQ * SPAD;
  float* s_   = (float*)(PvT + NSEQ * SPAD);
  float* ss_  = s_ + 128;
  float* inv_ = ss_ + 128;
  float* den2 = inv_ + 128;
  const int blk = blockIdx.x, bh = blk >> 3, lc = blk & 7;  // 8 l's per block
  const int t = threadIdx.x, w = t >> 6, lane = t & 63;
  const int r0 = w << 5;
  f32x4 att[2][8];
#pragma unroll
  for (int a = 0; a < 2; ++a)
#pragma unroll
    for (int b = 0; b < 8; ++b) att[a][b] = 0;
  for (int q = 0; q < 8; ++q) {
    const int l = (lc << 3) + q;
    const float wl = ws[OFF_W + bh * 64 + l];
    build_PT(ws + OFF_X + (size_t)bh * NSEQ * DIMH + l, PuT, s_, ss_, inv_, den2, t);
    build_PT(ws + OFF_Y + (size_t)bh * NSEQ * DIMH + l, PvT, s_, ss_, inv_, den2, t);
    f32x4 acc[2][8];
#pragma unroll
    for (int a = 0; a < 2; ++a)
#pragma unroll
      for (int b = 0; b < 8; ++b) acc[a][b] = 0;
#pragma unroll
    for (int kc = 0; kc < 4; ++kc) {
      const int k0 = kc << 5;
      f16x8 a0 = fragPT(PuT, r0, k0, lane);
      f16x8 a1 = fragPT(PuT, r0 + 16, k0, lane);
#pragma unroll
      for (int fj = 0; fj < 8; ++fj) {
        f16x8 b = fragPT(PvT, fj << 4, k0, lane);
        acc[0][fj] = __builtin_amdgcn_mfma_f32_16x16x32_f16(a0, b, acc[0][fj], 0, 0, 0);
        acc[1][fj] = __builtin_amdgcn_mfma_f32_16x16x32_f16(a1, b, acc[1][fj], 0, 0, 0);
      }
    }
#pragma unroll
    for (int a = 0; a < 2; ++a)
#pragma unroll
      for (int b = 0; b < 8; ++b) att[a][b] += wl * acc[a][b];
  }
  float* A = attn + (size_t)bh * NSEQ * NSEQ;
  const int cr = r0 + ((lane >> 4) << 2), cc = lane & 15;
#pragma unroll
  for (int fi = 0; fi < 2; ++fi)
#pragma unroll
    for (int fj = 0; fj < 8; ++fj)
#pragma unroll
      for (int r = 0; r < 4; ++r)
        atomicAdd(&A[(cr + (fi << 4) + r) * NSEQ + (fj << 4) + cc], att[fi][fj][r]);
}

// ---------------- K6a: oh = attn @ V (per head), scattered to [b*n][512] ----------------
__global__ __launch_bounds__(256) void k_av(const float* __restrict__ attn, float* __restrict__ ws) {
  extern __shared__ float sm[];
  float* As = sm;                 // 128*129 padded
  float* Vs = sm + 128 * 129;     // 128*64
  const int bh = blockIdx.x; const int t = threadIdx.x;
  const float* Ag = attn + (size_t)bh * 16384;
  const float* Vg = ws + OFF_V + (size_t)bh * 8192;
  for (int idx = t; idx < 16384; idx += 256) {
    int i = idx >> 7, j = idx & 127;
    As[i * 129 + j] = Ag[idx];
  }
  for (int idx = t; idx < 8192; idx += 256) Vs[idx] = Vg[idx];
  __syncthreads();
  const int i = t >> 1, d0 = (t & 1) << 5;
  float acc[32] = {};
  for (int j = 0; j < NSEQ; ++j) {
    float a = As[i * 129 + j];
#pragma unroll
    for (int dd = 0; dd < 32; ++dd) acc[dd] += a * Vs[j * DIMH + d0 + dd];
  }
  const int b = bh >> 3, h = bh & 7;
  float* o = ws + OFF_OH + ((size_t)(b * NSEQ + i)) * DMODEL + h * DIMH + d0;
#pragma unroll
  for (int dd = 0; dd < 32; ++dd) o[dd] = acc[dd];
}

// ---------------- K6b: out = oh @ w_out^T + b_out ----------------
__global__ __launch_bounds__(256) void k_out(const float* __restrict__ oh,
                                             const float* __restrict__ wout,
                                             const float* __restrict__ bout,
                                             float* __restrict__ out) {
  __shared__ float as_[64][65];
  __shared__ float bs_[64][65];
  const int r0 = blockIdx.x * 64, c0 = blockIdx.y * 64;
  const int t = threadIdx.x;
  const int tr = (t >> 4) << 2, tc = (t & 15) << 2;
  float acc[4][4] = {};
  for (int k0 = 0; k0 < 512; k0 += 64) {
    for (int idx = t; idx < 64 * 64; idx += 256) {
      int i = idx >> 6, j = idx & 63;
      as_[i][j] = oh[(size_t)(r0 + i) * 512 + k0 + j];
      bs_[i][j] = wout[(size_t)(c0 + i) * 512 + k0 + j];
    }
    __syncthreads();
    for (int kk = 0; kk < 64; ++kk) {
      float a[4], b[4];
#pragma unroll
      for (int u = 0; u < 4; ++u) { a[u] = as_[tr + u][kk]; b[u] = bs_[tc + u][kk]; }
#pragma unroll
      for (int u = 0; u < 4; ++u)
#pragma unroll
        for (int w = 0; w < 4; ++w) acc[u][w] += a[u] * b[w];
    }
    __syncthreads();
  }
#pragma unroll
  for (int u = 0; u < 4; ++u)
#pragma unroll
    for (int w = 0; w < 4; ++w)
      out[(size_t)(r0 + tr + u) * 512 + c0 + tc + w] = acc[u][w] + bout[c0 + tc + w];
}

extern "C" void kernel_launch(void* const* d_in, const int* in_sizes, int n_in,
                              void* d_out, int out_size, void* d_ws, size_t ws_size,
                              hipStream_t stream) {
  (void)in_sizes; (void)n_in; (void)out_size; (void)ws_size;
  const float* x    = (const float*)d_in[0];
  const float* wqkv = (const float*)d_in[1];
  const float* wout = (const float*)d_in[2];
  const float* bout = (const float*)d_in[3];
  float* out  = (float*)d_out;           // [4,128,512] = 262144 floats
  float* attn = out + 262144;            // [4,8,128,128] = 524288 floats
  float* ws   = (float*)d_ws;

  hipMemsetAsync(attn, 0, 524288 * sizeof(float), stream);
  k_qkv<<<dim3(8, 24), 256, 0, stream>>>(x, wqkv, ws);
  k_cost<<<32, 256, (128 * 65 + 128 * 64 + 256) * 4, stream>>>(ws);
  k_phase1<<<2048, 256, PH_SMEM, stream>>>(ws);
  k_weights<<<32, 64, 0, stream>>>(ws);
  k_phase2<<<256, 256, PH_SMEM, stream>>>(ws, attn);
  k_av<<<32, 256, (128 * 129 + 128 * 64) * 4, stream>>>(attn, ws);
  k_out<<<dim3(8, 8), 256, 0, stream>>>(ws + OFF_OH, wout, bout, out);
}